// Round 5
// baseline (2945.802 us; speedup 1.0000x reference)
//
#include <hip/hip_runtime.h>

// ---------------------------------------------------------------------------
// Child-Sum TreeLSTM, complete binary tree, level-wise bottom-up, bf16 MFMA.
// Round 5: persistent blocks, per-tile software pipeline (register-staged
// global loads for tile t+G issued under tile t's compute), bf16 h scratch
// (ping-pong) to halve child-h traffic, ping-pong level-local c buffers.
// Memory-bound op (~6:1) -> goal is continuous streaming, not MFMA util.
//
// mfma_f32_32x32x16_bf16: A lane: row=l&31, k=(l>>5)*8+e  (16B ds_read)
//                         B lane: col=l&31, k=(l>>5)*8+e = W[col][k] (16B)
//                         D: col=l&31, row=(r&3)+8*(r>>2)+4*(l>>5), r=0..15
// ---------------------------------------------------------------------------

typedef __attribute__((ext_vector_type(8))) short bf16x8;
typedef __attribute__((ext_vector_type(8))) unsigned short us8;
typedef __attribute__((ext_vector_type(16))) float f32x16;

#define LSTR 264   // 256 + 8 bf16 pad (row stride 528 B; measured 0 conflicts)
#define MT 32      // nodes per tile

#define MFMA32(A, B, C) __builtin_amdgcn_mfma_f32_32x32x16_bf16(A, B, C, 0, 0, 0)

__device__ __forceinline__ unsigned short f2b(float f) {
  unsigned int u = __builtin_bit_cast(unsigned int, f);
  u = u + 0x7FFFu + ((u >> 16) & 1u);   // RNE
  return (unsigned short)(u >> 16);
}
__device__ __forceinline__ float bf2f(unsigned short u) {
  unsigned int v = (unsigned int)u << 16;
  return __builtin_bit_cast(float, v);
}
__device__ __forceinline__ us8 pack8(float4 a, float4 b) {
  us8 r;
  r[0] = f2b(a.x); r[1] = f2b(a.y); r[2] = f2b(a.z); r[3] = f2b(a.w);
  r[4] = f2b(b.x); r[5] = f2b(b.y); r[6] = f2b(b.z); r[7] = f2b(b.w);
  return r;
}
__device__ __forceinline__ float sigm(float x) { return 1.0f / (1.0f + __expf(-x)); }
__device__ __forceinline__ float tanh_f(float x) { return 2.0f / (1.0f + __expf(-2.0f * x)) - 1.0f; }
__device__ __forceinline__ f32x16 zz16() {
  f32x16 v;
  #pragma unroll
  for (int i = 0; i < 16; ++i) v[i] = 0.f;
  return v;
}

__global__ void pack_w(const float* __restrict__ a,  // Wioux 768x256
                       const float* __restrict__ b,  // Wiouh 768x256
                       const float* __restrict__ c,  // Wfx   256x256
                       const float* __restrict__ d,  // Wfh   256x256
                       unsigned short* __restrict__ out) {
  int i = blockIdx.x * blockDim.x + threadIdx.x;  // 0 .. 524287
  const int A = 768 * 256;
  const int B = A + 768 * 256;
  const int C = B + 256 * 256;
  float v;
  if (i < A)      v = a[i];
  else if (i < B) v = b[i - A];
  else if (i < C) v = c[i - B];
  else            v = d[i - C];
  out[i] = f2b(v);
}

template<int LEAF>
__global__ __launch_bounds__(512, 2) void level_k(
    const float* __restrict__ x_in,
    const unsigned short* __restrict__ Wx,     // bf16 Wioux [768][256]
    const unsigned short* __restrict__ Wh,     // bf16 Wiouh [768][256]
    const unsigned short* __restrict__ Wfxw,   // bf16 Wfx   [256][256]
    const unsigned short* __restrict__ Wfhw,   // bf16 Wfh   [256][256]
    const float* __restrict__ bioux,
    const float* __restrict__ bfx,
    const float* __restrict__ fb,
    float* __restrict__ h_all,                 // d_out + 512, global node idx
    float* __restrict__ c_cur,                 // level-local [L][256] f32
    const float* __restrict__ c_next,          // child level-local f32
    unsigned short* __restrict__ hb_cur,       // level-local [L][256] bf16
    const unsigned short* __restrict__ hb_next,// child level-local bf16
    float* __restrict__ out0,                  // d_out (h_root | c_root)
    int s, int L, int T, int root)
{
  extern __shared__ unsigned short sm[];
  unsigned short* Xs  = sm;                       // [MT][LSTR]
  unsigned short* H1s = sm + MT * LSTR;
  unsigned short* H2s = sm + 2 * MT * LSTR;
  unsigned short* HSs = sm + 3 * MT * LSTR;

  const int tid = threadIdx.x;
  const int G   = gridDim.x;

  // staging partition: thread -> (row 0..31, 16-elem chunk)
  const int row = tid >> 4;
  const int ec  = (tid & 15) * 16;

  // MFMA ids
  const int lane = tid & 63;
  const int w    = tid >> 6;
  const int lr   = lane & 31;
  const int kh   = lane >> 5;
  const int koff = kh * 8;
  const int colc = w * 32 + lr;

  const unsigned short* wxp  = Wx   + (size_t)colc * 256;  // i (o:+65536, u:+131072)
  const unsigned short* whp  = Wh   + (size_t)colc * 256;
  const unsigned short* wfxp = Wfxw + (size_t)colc * 256;
  const unsigned short* wfhp = Wfhw + (size_t)colc * 256;

  const float bi_ = bioux[colc];
  const float bo_ = bioux[256 + colc];
  const float bu_ = bioux[512 + colc];
  const float bf_ = LEAF ? 0.f : (bfx[colc] + fb[colc]);

  // ---- prologue: issue loads for first tile ----
  int t = blockIdx.x;
  float4 px0, px1, px2, px3;
  us8 h1a, h1b, h2a, h2b;
  if (t < T) {
    const float* xp = x_in + ((size_t)(s + t * MT + row)) * 256 + ec;
    px0 = *(const float4*)xp;       px1 = *(const float4*)(xp + 4);
    px2 = *(const float4*)(xp + 8); px3 = *(const float4*)(xp + 12);
    if (!LEAF) {
      const unsigned short* hq = hb_next + ((size_t)(2 * (t * MT + row))) * 256 + ec;
      h1a = *(const us8*)hq;         h1b = *(const us8*)(hq + 8);
      h2a = *(const us8*)(hq + 256); h2b = *(const us8*)(hq + 264);
    }
  }

  for (; t < T; t += G) {
    const int nb0 = t * MT;

    // ---- commit staged regs to LDS ----
    __syncthreads();   // prior tile's LDS readers done
    *(us8*)(Xs + row * LSTR + ec)     = pack8(px0, px1);
    *(us8*)(Xs + row * LSTR + ec + 8) = pack8(px2, px3);
    if (!LEAF) {
      *(us8*)(H1s + row * LSTR + ec)     = h1a;
      *(us8*)(H1s + row * LSTR + ec + 8) = h1b;
      *(us8*)(H2s + row * LSTR + ec)     = h2a;
      *(us8*)(H2s + row * LSTR + ec + 8) = h2b;
      us8 sa, sb;
      #pragma unroll
      for (int e = 0; e < 8; ++e) {
        sa[e] = f2b(bf2f(h1a[e]) + bf2f(h2a[e]));
        sb[e] = f2b(bf2f(h1b[e]) + bf2f(h2b[e]));
      }
      *(us8*)(HSs + row * LSTR + ec)     = sa;
      *(us8*)(HSs + row * LSTR + ec + 8) = sb;
    }

    // ---- issue next tile's loads (overlap with this tile's compute) ----
    const int tn = t + G;
    if (tn < T) {
      const float* xp = x_in + ((size_t)(s + tn * MT + row)) * 256 + ec;
      px0 = *(const float4*)xp;       px1 = *(const float4*)(xp + 4);
      px2 = *(const float4*)(xp + 8); px3 = *(const float4*)(xp + 12);
      if (!LEAF) {
        const unsigned short* hq = hb_next + ((size_t)(2 * (tn * MT + row))) * 256 + ec;
        h1a = *(const us8*)hq;         h1b = *(const us8*)(hq + 8);
        h2a = *(const us8*)(hq + 256); h2b = *(const us8*)(hq + 264);
      }
    }
    __syncthreads();   // LDS tile ready

    if (!LEAF) {
      // ---- P1: xf = x @ Wfx^T ----
      f32x16 axf = zz16();
      for (int kt = 0; kt < 16; ++kt) {
        const int k0 = kt * 16 + koff;
        bf16x8 bfxv = *(const bf16x8*)(wfxp + k0);
        bf16x8 ax   = *(const bf16x8*)(Xs + lr * LSTR + k0);
        axf = MFMA32(ax, bfxv, axf);
      }
      float xf[16];
      #pragma unroll
      for (int r = 0; r < 16; ++r) xf[r] = axf[r] + bf_;

      // ---- children c gathers (hide under P2) ----
      float c1v[16], c2v[16];
      #pragma unroll
      for (int r = 0; r < 16; ++r) {
        const int m = (r & 3) + 8 * (r >> 2) + 4 * kh;
        const size_t cb = (size_t)(2 * (nb0 + m)) * 256 + colc;
        c1v[r] = c_next[cb];
        c2v[r] = c_next[cb + 256];
      }

      // ---- P2: f1 = h1@Wfh^T, f2 = h2@Wfh^T ----
      f32x16 f1 = zz16(), f2 = zz16();
      for (int kt = 0; kt < 16; ++kt) {
        const int k0 = kt * 16 + koff;
        bf16x8 bfh = *(const bf16x8*)(wfhp + k0);
        bf16x8 a1  = *(const bf16x8*)(H1s + lr * LSTR + k0);
        bf16x8 a2  = *(const bf16x8*)(H2s + lr * LSTR + k0);
        f1 = MFMA32(a1, bfh, f1);
        f2 = MFMA32(a2, bfh, f2);
      }
      float cv[16];
      #pragma unroll
      for (int r = 0; r < 16; ++r)
        cv[r] = sigm(xf[r] + f1[r]) * c1v[r] + sigm(xf[r] + f2[r]) * c2v[r];

      // ---- P3: i,o,u = x@Wioux^T + hsum@Wiouh^T ----
      f32x16 ai = zz16(), ao = zz16(), au = zz16();
      for (int kt = 0; kt < 16; ++kt) {
        const int k0 = kt * 16 + koff;
        bf16x8 bix = *(const bf16x8*)(wxp + k0);
        bf16x8 box = *(const bf16x8*)(wxp + 65536 + k0);
        bf16x8 bux = *(const bf16x8*)(wxp + 131072 + k0);
        bf16x8 bih = *(const bf16x8*)(whp + k0);
        bf16x8 boh = *(const bf16x8*)(whp + 65536 + k0);
        bf16x8 buh = *(const bf16x8*)(whp + 131072 + k0);
        bf16x8 ax  = *(const bf16x8*)(Xs  + lr * LSTR + k0);
        bf16x8 ahs = *(const bf16x8*)(HSs + lr * LSTR + k0);
        ai = MFMA32(ax,  bix, ai);
        ao = MFMA32(ax,  box, ao);
        au = MFMA32(ax,  bux, au);
        ai = MFMA32(ahs, bih, ai);
        ao = MFMA32(ahs, boh, ao);
        au = MFMA32(ahs, buh, au);
      }

      // ---- epilogue ----
      #pragma unroll
      for (int r = 0; r < 16; ++r) {
        const int m = (r & 3) + 8 * (r >> 2) + 4 * kh;
        const int j = nb0 + m;
        if (j >= L) continue;
        const size_t n = (size_t)(s + j);
        const float c_ = cv[r] + sigm(ai[r] + bi_) * tanh_f(au[r] + bu_);
        const float hv = sigm(ao[r] + bo_) * tanh_f(c_);
        h_all[n * 256 + colc] = hv;
        c_cur[(size_t)j * 256 + colc] = c_;
        hb_cur[(size_t)j * 256 + colc] = f2b(hv);
        if (root && j == 0) { out0[colc] = hv; out0[256 + colc] = c_; }
      }
    } else {
      // ---- leaves: i,o,u from x only ----
      f32x16 ai = zz16(), ao = zz16(), au = zz16();
      for (int kt = 0; kt < 16; ++kt) {
        const int k0 = kt * 16 + koff;
        bf16x8 bix = *(const bf16x8*)(wxp + k0);
        bf16x8 box = *(const bf16x8*)(wxp + 65536 + k0);
        bf16x8 bux = *(const bf16x8*)(wxp + 131072 + k0);
        bf16x8 ax  = *(const bf16x8*)(Xs + lr * LSTR + k0);
        ai = MFMA32(ax, bix, ai);
        ao = MFMA32(ax, box, ao);
        au = MFMA32(ax, bux, au);
      }
      #pragma unroll
      for (int r = 0; r < 16; ++r) {
        const int m = (r & 3) + 8 * (r >> 2) + 4 * kh;
        const int j = nb0 + m;
        if (j >= L) continue;
        const size_t n = (size_t)(s + j);
        const float c_ = sigm(ai[r] + bi_) * tanh_f(au[r] + bu_);
        const float hv = sigm(ao[r] + bo_) * tanh_f(c_);
        h_all[n * 256 + colc] = hv;
        c_cur[(size_t)j * 256 + colc] = c_;
        hb_cur[(size_t)j * 256 + colc] = f2b(hv);
      }
    }
  }
}

extern "C" void kernel_launch(void* const* d_in, const int* in_sizes, int n_in,
                              void* d_out, int out_size, void* d_ws, size_t ws_size,
                              hipStream_t stream) {
  const float* inputs = (const float*)d_in[0];
  const float* Wioux  = (const float*)d_in[1];
  const float* bioux  = (const float*)d_in[2];
  const float* Wiouh  = (const float*)d_in[3];
  const float* Wfx    = (const float*)d_in[4];
  const float* bfx    = (const float*)d_in[5];
  const float* Wfh    = (const float*)d_in[6];
  const float* fb     = (const float*)d_in[7];

  const int N = in_sizes[0] / 256;       // 262143
  int depth = 0;
  while (((1 << depth) - 1) < N) ++depth;  // 18
  const int LF = (N + 1) / 2;            // 131072 leaves

  float* out   = (float*)d_out;
  float* h_all = out + 512;

  // ws carve: c ping-pong (f32, level-local), hb ping-pong (bf16), weights
  char* p = (char*)d_ws;
  float* c_even = (float*)p;                 p += (size_t)(LF / 2) * 256 * 4;  //  67 MB (levels 0,2,..,16)
  float* c_odd  = (float*)p;                 p += (size_t)LF * 256 * 4;        // 134 MB (levels 1,3,..,17)
  unsigned short* hb_even = (unsigned short*)p; p += (size_t)(LF / 2) * 256 * 2; // 33.5 MB
  unsigned short* hb_odd  = (unsigned short*)p; p += (size_t)LF * 256 * 2;       //  67 MB
  unsigned short* wb = (unsigned short*)p;   // 1 MB

  pack_w<<<2048, 256, 0, stream>>>(Wioux, Wiouh, Wfx, Wfh, wb);

  const unsigned short* pWx  = wb;
  const unsigned short* pWh  = wb + 768 * 256;
  const unsigned short* pWfx = wb + 2 * 768 * 256;
  const unsigned short* pWfh = wb + 2 * 768 * 256 + 256 * 256;

  for (int d = depth - 1; d >= 0; --d) {
    const int L = 1 << d;
    const int s = L - 1;
    const int T = (L + MT - 1) / MT;
    const int G = T < 512 ? T : 512;
    float* c_cur = (d & 1) ? c_odd : c_even;
    const float* c_next = ((d + 1) & 1) ? c_odd : c_even;
    unsigned short* hb_cur = (d & 1) ? hb_odd : hb_even;
    const unsigned short* hb_next = ((d + 1) & 1) ? hb_odd : hb_even;
    if (d == depth - 1) {
      level_k<1><<<G, 512, (size_t)MT * LSTR * 2, stream>>>(
          inputs, pWx, pWh, pWfx, pWfh, bioux, bfx, fb,
          h_all, c_cur, c_next, hb_cur, hb_next, out, s, L, T, 0);
    } else {
      level_k<0><<<G, 512, (size_t)4 * MT * LSTR * 2, stream>>>(
          inputs, pWx, pWh, pWfx, pWfh, bioux, bfx, fb,
          h_all, c_cur, c_next, hb_cur, hb_next, out, s, L, T, (d == 0) ? 1 : 0);
    }
  }
}

// Round 6
// 2874.586 us; speedup vs baseline: 1.0248x; 1.0248x over previous
//
#include <hip/hip_runtime.h>

// ---------------------------------------------------------------------------
// Child-Sum TreeLSTM, complete binary tree, level-wise bottom-up, bf16 MFMA.
// Round 6: persistent blocks + register-staged pipeline (fixed R5's spill):
//   - x pre-converted to bf16 (interior nodes) -> staged x is 8 regs
//   - c stored as bf16 ping-pong (halves c traffic + gather regs usage ok)
//   - no HSs buffer: hsum@Wiouh done as h1@W + h2@W (9 MFMA/kt in P3)
//   - staged regs = 24 (interior) / 16 (leaf); peak live ~120 < 128 cap
// Memory-bound op -> goal is continuous HBM streaming.
//
// mfma_f32_32x32x16_bf16: A lane: row=l&31, k=(l>>5)*8+e  (16B ds_read)
//                         B lane: col=l&31, k=(l>>5)*8+e = W[col][k] (16B)
//                         D: col=l&31, row=(r&3)+8*(r>>2)+4*(l>>5), r=0..15
// ---------------------------------------------------------------------------

typedef __attribute__((ext_vector_type(8))) short bf16x8;
typedef __attribute__((ext_vector_type(8))) unsigned short us8;
typedef __attribute__((ext_vector_type(16))) float f32x16;

#define LSTR 264   // 256 + 8 bf16 pad (row stride 528 B; 0 measured conflicts)
#define MT 32      // nodes per tile

#define MFMA32(A, B, C) __builtin_amdgcn_mfma_f32_32x32x16_bf16(A, B, C, 0, 0, 0)

__device__ __forceinline__ unsigned short f2b(float f) {
  unsigned int u = __builtin_bit_cast(unsigned int, f);
  u = u + 0x7FFFu + ((u >> 16) & 1u);   // RNE
  return (unsigned short)(u >> 16);
}
__device__ __forceinline__ float bf2f(unsigned short u) {
  unsigned int v = (unsigned int)u << 16;
  return __builtin_bit_cast(float, v);
}
__device__ __forceinline__ us8 pack8(float4 a, float4 b) {
  us8 r;
  r[0] = f2b(a.x); r[1] = f2b(a.y); r[2] = f2b(a.z); r[3] = f2b(a.w);
  r[4] = f2b(b.x); r[5] = f2b(b.y); r[6] = f2b(b.z); r[7] = f2b(b.w);
  return r;
}
__device__ __forceinline__ float sigm(float x) { return 1.0f / (1.0f + __expf(-x)); }
__device__ __forceinline__ float tanh_f(float x) { return 2.0f / (1.0f + __expf(-2.0f * x)) - 1.0f; }
__device__ __forceinline__ f32x16 zz16() {
  f32x16 v;
  #pragma unroll
  for (int i = 0; i < 16; ++i) v[i] = 0.f;
  return v;
}

__global__ void pack_w(const float* __restrict__ a,  // Wioux 768x256
                       const float* __restrict__ b,  // Wiouh 768x256
                       const float* __restrict__ c,  // Wfx   256x256
                       const float* __restrict__ d,  // Wfh   256x256
                       unsigned short* __restrict__ out) {
  int i = blockIdx.x * blockDim.x + threadIdx.x;  // 0 .. 524287
  const int A = 768 * 256;
  const int B = A + 768 * 256;
  const int C = B + 256 * 256;
  float v;
  if (i < A)      v = a[i];
  else if (i < B) v = b[i - A];
  else if (i < C) v = c[i - B];
  else            v = d[i - C];
  out[i] = f2b(v);
}

// convert interior-node x rows to bf16 (8 elems/thread)
__global__ void conv_x(const float* __restrict__ x, unsigned short* __restrict__ xb, int n8) {
  int i = blockIdx.x * blockDim.x + threadIdx.x;
  if (i >= n8) return;
  float4 a = *(const float4*)(x + (size_t)i * 8);
  float4 b = *(const float4*)(x + (size_t)i * 8 + 4);
  *(us8*)(xb + (size_t)i * 8) = pack8(a, b);
}

template<int LEAF>
__global__ __launch_bounds__(512, 2) void level_k(
    const float* __restrict__ xf32,            // used by leaf
    const unsigned short* __restrict__ xb,     // used by interior (global node idx)
    const unsigned short* __restrict__ Wx,     // bf16 Wioux [768][256]
    const unsigned short* __restrict__ Wh,     // bf16 Wiouh [768][256]
    const unsigned short* __restrict__ Wfxw,   // bf16 Wfx   [256][256]
    const unsigned short* __restrict__ Wfhw,   // bf16 Wfh   [256][256]
    const float* __restrict__ bioux,
    const float* __restrict__ bfx,
    const float* __restrict__ fb,
    float* __restrict__ h_all,                 // d_out + 512, global node idx
    unsigned short* __restrict__ cb_cur,       // level-local [L][256] bf16
    const unsigned short* __restrict__ cb_next,
    unsigned short* __restrict__ hb_cur,       // level-local [L][256] bf16
    const unsigned short* __restrict__ hb_next,
    float* __restrict__ out0,                  // d_out (h_root | c_root)
    int s, int L, int T, int root)
{
  extern __shared__ unsigned short sm[];
  unsigned short* Xs  = sm;                       // [MT][LSTR]
  unsigned short* H1s = sm + MT * LSTR;
  unsigned short* H2s = sm + 2 * MT * LSTR;

  const int tid = threadIdx.x;
  const int G   = gridDim.x;

  // staging partition: thread -> (row 0..31, 16-elem chunk)
  const int row = tid >> 4;
  const int ec  = (tid & 15) * 16;

  // MFMA ids
  const int lane = tid & 63;
  const int w    = tid >> 6;
  const int lr   = lane & 31;
  const int kh   = lane >> 5;
  const int koff = kh * 8;
  const int colc = w * 32 + lr;

  const unsigned short* wxp  = Wx   + (size_t)colc * 256;  // i (o:+65536, u:+131072)
  const unsigned short* whp  = Wh   + (size_t)colc * 256;
  const unsigned short* wfxp = Wfxw + (size_t)colc * 256;
  const unsigned short* wfhp = Wfhw + (size_t)colc * 256;

  const float bi_ = bioux[colc];
  const float bo_ = bioux[256 + colc];
  const float bu_ = bioux[512 + colc];
  const float bf_ = LEAF ? 0.f : (bfx[colc] + fb[colc]);

  // ---- staged registers ----
  us8 sx0, sx1, sh10, sh11, sh20, sh21;
  float4 fx0, fx1, fx2, fx3;

  int t = blockIdx.x;
  if (t < T) {   // prologue loads
    if (LEAF) {
      const float* xp = xf32 + ((size_t)(s + t * MT + row)) * 256 + ec;
      fx0 = *(const float4*)xp;       fx1 = *(const float4*)(xp + 4);
      fx2 = *(const float4*)(xp + 8); fx3 = *(const float4*)(xp + 12);
    } else {
      const unsigned short* xq = xb + ((size_t)(s + t * MT + row)) * 256 + ec;
      sx0 = *(const us8*)xq; sx1 = *(const us8*)(xq + 8);
      const unsigned short* hq = hb_next + ((size_t)(2 * (t * MT + row))) * 256 + ec;
      sh10 = *(const us8*)hq;         sh11 = *(const us8*)(hq + 8);
      sh20 = *(const us8*)(hq + 256); sh21 = *(const us8*)(hq + 264);
    }
  }

  for (; t < T; t += G) {
    const int nb0 = t * MT;

    __syncthreads();   // prior tile's LDS readers done
    if (LEAF) {
      *(us8*)(Xs + row * LSTR + ec)     = pack8(fx0, fx1);
      *(us8*)(Xs + row * LSTR + ec + 8) = pack8(fx2, fx3);
    } else {
      *(us8*)(Xs  + row * LSTR + ec)     = sx0;
      *(us8*)(Xs  + row * LSTR + ec + 8) = sx1;
      *(us8*)(H1s + row * LSTR + ec)     = sh10;
      *(us8*)(H1s + row * LSTR + ec + 8) = sh11;
      *(us8*)(H2s + row * LSTR + ec)     = sh20;
      *(us8*)(H2s + row * LSTR + ec + 8) = sh21;
    }

    // ---- issue next tile's loads (overlap with this tile's compute) ----
    const int tn = t + G;
    if (tn < T) {
      if (LEAF) {
        const float* xp = xf32 + ((size_t)(s + tn * MT + row)) * 256 + ec;
        fx0 = *(const float4*)xp;       fx1 = *(const float4*)(xp + 4);
        fx2 = *(const float4*)(xp + 8); fx3 = *(const float4*)(xp + 12);
      } else {
        const unsigned short* xq = xb + ((size_t)(s + tn * MT + row)) * 256 + ec;
        sx0 = *(const us8*)xq; sx1 = *(const us8*)(xq + 8);
        const unsigned short* hq = hb_next + ((size_t)(2 * (tn * MT + row))) * 256 + ec;
        sh10 = *(const us8*)hq;         sh11 = *(const us8*)(hq + 8);
        sh20 = *(const us8*)(hq + 256); sh21 = *(const us8*)(hq + 264);
      }
    }
    __syncthreads();   // LDS tile ready

    if (!LEAF) {
      // ---- P1: axf = x @ Wfx^T (one plane live) ----
      f32x16 axf = zz16();
      for (int kt = 0; kt < 16; ++kt) {
        const int k0 = kt * 16 + koff;
        bf16x8 bfxv = *(const bf16x8*)(wfxp + k0);
        bf16x8 ax   = *(const bf16x8*)(Xs + lr * LSTR + k0);
        axf = MFMA32(ax, bfxv, axf);
      }
      f32x16 f1 = axf, f2 = axf;

      // ---- children c gathers (bf16; hide under P2) ----
      float c1v[16], c2v[16];
      #pragma unroll
      for (int r = 0; r < 16; ++r) {
        const int m = (r & 3) + 8 * (r >> 2) + 4 * kh;
        const size_t cbo = (size_t)(2 * (nb0 + m)) * 256 + colc;
        c1v[r] = bf2f(cb_next[cbo]);
        c2v[r] = bf2f(cb_next[cbo + 256]);
      }

      // ---- P2: f1 += h1@Wfh^T, f2 += h2@Wfh^T (B-frag shared) ----
      for (int kt = 0; kt < 16; ++kt) {
        const int k0 = kt * 16 + koff;
        bf16x8 bfh = *(const bf16x8*)(wfhp + k0);
        bf16x8 a1  = *(const bf16x8*)(H1s + lr * LSTR + k0);
        bf16x8 a2  = *(const bf16x8*)(H2s + lr * LSTR + k0);
        f1 = MFMA32(a1, bfh, f1);
        f2 = MFMA32(a2, bfh, f2);
      }
      float cv[16];
      #pragma unroll
      for (int r = 0; r < 16; ++r)
        cv[r] = sigm(f1[r] + bf_) * c1v[r] + sigm(f2[r] + bf_) * c2v[r];

      // ---- P3: i,o,u = x@Wioux^T + h1@Wiouh^T + h2@Wiouh^T ----
      f32x16 ai = zz16(), ao = zz16(), au = zz16();
      for (int kt = 0; kt < 16; ++kt) {
        const int k0 = kt * 16 + koff;
        bf16x8 bix = *(const bf16x8*)(wxp + k0);
        bf16x8 box = *(const bf16x8*)(wxp + 65536 + k0);
        bf16x8 bux = *(const bf16x8*)(wxp + 131072 + k0);
        bf16x8 bih = *(const bf16x8*)(whp + k0);
        bf16x8 boh = *(const bf16x8*)(whp + 65536 + k0);
        bf16x8 buh = *(const bf16x8*)(whp + 131072 + k0);
        bf16x8 ax  = *(const bf16x8*)(Xs  + lr * LSTR + k0);
        bf16x8 a1  = *(const bf16x8*)(H1s + lr * LSTR + k0);
        bf16x8 a2  = *(const bf16x8*)(H2s + lr * LSTR + k0);
        ai = MFMA32(ax, bix, ai);
        ao = MFMA32(ax, box, ao);
        au = MFMA32(ax, bux, au);
        ai = MFMA32(a1, bih, ai);
        ao = MFMA32(a1, boh, ao);
        au = MFMA32(a1, buh, au);
        ai = MFMA32(a2, bih, ai);
        ao = MFMA32(a2, boh, ao);
        au = MFMA32(a2, buh, au);
      }

      // ---- epilogue ----
      #pragma unroll
      for (int r = 0; r < 16; ++r) {
        const int m = (r & 3) + 8 * (r >> 2) + 4 * kh;
        const int j = nb0 + m;
        if (j >= L) continue;
        const size_t n = (size_t)(s + j);
        const float c_ = cv[r] + sigm(ai[r] + bi_) * tanh_f(au[r] + bu_);
        const float hv = sigm(ao[r] + bo_) * tanh_f(c_);
        h_all[n * 256 + colc] = hv;
        cb_cur[(size_t)j * 256 + colc] = f2b(c_);
        hb_cur[(size_t)j * 256 + colc] = f2b(hv);
        if (root && j == 0) { out0[colc] = hv; out0[256 + colc] = c_; }
      }
    } else {
      // ---- leaves: i,o,u from x only ----
      f32x16 ai = zz16(), ao = zz16(), au = zz16();
      for (int kt = 0; kt < 16; ++kt) {
        const int k0 = kt * 16 + koff;
        bf16x8 bix = *(const bf16x8*)(wxp + k0);
        bf16x8 box = *(const bf16x8*)(wxp + 65536 + k0);
        bf16x8 bux = *(const bf16x8*)(wxp + 131072 + k0);
        bf16x8 ax  = *(const bf16x8*)(Xs + lr * LSTR + k0);
        ai = MFMA32(ax, bix, ai);
        ao = MFMA32(ax, box, ao);
        au = MFMA32(ax, bux, au);
      }
      #pragma unroll
      for (int r = 0; r < 16; ++r) {
        const int m = (r & 3) + 8 * (r >> 2) + 4 * kh;
        const int j = nb0 + m;
        if (j >= L) continue;
        const size_t n = (size_t)(s + j);
        const float c_ = sigm(ai[r] + bi_) * tanh_f(au[r] + bu_);
        const float hv = sigm(ao[r] + bo_) * tanh_f(c_);
        h_all[n * 256 + colc] = hv;
        cb_cur[(size_t)j * 256 + colc] = f2b(c_);
        hb_cur[(size_t)j * 256 + colc] = f2b(hv);
      }
    }
  }
}

extern "C" void kernel_launch(void* const* d_in, const int* in_sizes, int n_in,
                              void* d_out, int out_size, void* d_ws, size_t ws_size,
                              hipStream_t stream) {
  const float* inputs = (const float*)d_in[0];
  const float* Wioux  = (const float*)d_in[1];
  const float* bioux  = (const float*)d_in[2];
  const float* Wiouh  = (const float*)d_in[3];
  const float* Wfx    = (const float*)d_in[4];
  const float* bfx    = (const float*)d_in[5];
  const float* Wfh    = (const float*)d_in[6];
  const float* fb     = (const float*)d_in[7];

  const int N = in_sizes[0] / 256;       // 262143
  int depth = 0;
  while (((1 << depth) - 1) < N) ++depth;  // 18
  const int LF = (N + 1) / 2;            // 131072 leaves

  float* out   = (float*)d_out;
  float* h_all = out + 512;

  // ws carve (bytes): cb ping-pong bf16, hb ping-pong bf16, xb bf16, weights
  char* p = (char*)d_ws;
  unsigned short* cb_even = (unsigned short*)p; p += (size_t)(LF / 2) * 256 * 2; // 33.5 MB
  unsigned short* cb_odd  = (unsigned short*)p; p += (size_t)LF * 256 * 2;       // 67 MB
  unsigned short* hb_even = (unsigned short*)p; p += (size_t)(LF / 2) * 256 * 2; // 33.5 MB
  unsigned short* hb_odd  = (unsigned short*)p; p += (size_t)LF * 256 * 2;       // 67 MB
  unsigned short* xb      = (unsigned short*)p; p += (size_t)LF * 256 * 2;       // 67 MB
  unsigned short* wb      = (unsigned short*)p;                                  // 1 MB

  pack_w<<<2048, 256, 0, stream>>>(Wioux, Wiouh, Wfx, Wfh, wb);
  {
    const int n8 = ((LF - 1) * 256) / 8;   // interior-node elems / 8
    conv_x<<<(n8 + 255) / 256, 256, 0, stream>>>(inputs, xb, n8);
  }

  const unsigned short* pWx  = wb;
  const unsigned short* pWh  = wb + 768 * 256;
  const unsigned short* pWfx = wb + 2 * 768 * 256;
  const unsigned short* pWfh = wb + 2 * 768 * 256 + 256 * 256;

  for (int d = depth - 1; d >= 0; --d) {
    const int L = 1 << d;
    const int s = L - 1;
    const int T = (L + MT - 1) / MT;
    const int G = T < 512 ? T : 512;
    unsigned short* cb_cur = (d & 1) ? cb_odd : cb_even;
    const unsigned short* cb_next = ((d + 1) & 1) ? cb_odd : cb_even;
    unsigned short* hb_cur = (d & 1) ? hb_odd : hb_even;
    const unsigned short* hb_next = ((d + 1) & 1) ? hb_odd : hb_even;
    if (d == depth - 1) {
      level_k<1><<<G, 512, (size_t)MT * LSTR * 2, stream>>>(
          inputs, xb, pWx, pWh, pWfx, pWfh, bioux, bfx, fb,
          h_all, cb_cur, cb_next, hb_cur, hb_next, out, s, L, T, 0);
    } else {
      level_k<0><<<G, 512, (size_t)3 * MT * LSTR * 2, stream>>>(
          inputs, xb, pWx, pWh, pWfx, pWfh, bioux, bfx, fb,
          h_all, cb_cur, cb_next, hb_cur, hb_next, out, s, L, T, (d == 0) ? 1 : 0);
    }
  }
}

// Round 7
// 1469.231 us; speedup vs baseline: 2.0050x; 1.9565x over previous
//
#include <hip/hip_runtime.h>

// ---------------------------------------------------------------------------
// Child-Sum TreeLSTM, complete binary tree, level-wise bottom-up, bf16 MFMA.
// Round 7: single-plane passes to kill spill (R5/R6 spilled ~1.2 GB/dispatch):
//   P1 xf=x@Wfx -> P2a f1 (+c1 gather) -> P2b f2 (reuses xf regs)
//   -> issue next-tile staged loads -> P3i -> P3u -> P3o (one plane each,
//   #pragma unroll 1, A-frags re-read from LDS).
// Peak live ~115 VGPR < 128 cap (launch_bounds(512,2) == 2 blocks/CU here).
// Tripwire: WRITE_SIZE must equal real outputs (~1.35e5 KB on level 16).
//
// mfma_f32_32x32x16_bf16: A lane: row=l&31, k=(l>>5)*8+e  (16B ds_read)
//                         B lane: col=l&31, k=(l>>5)*8+e = W[col][k] (16B)
//                         D: col=l&31, row=(r&3)+8*(r>>2)+4*(l>>5), r=0..15
// ---------------------------------------------------------------------------

typedef __attribute__((ext_vector_type(8))) short bf16x8;
typedef __attribute__((ext_vector_type(8))) unsigned short us8;
typedef __attribute__((ext_vector_type(16))) float f32x16;

#define LSTR 264   // 256 + 8 bf16 pad (row stride 528 B)
#define MT 32      // nodes per tile

#define MFMA32(A, B, C) __builtin_amdgcn_mfma_f32_32x32x16_bf16(A, B, C, 0, 0, 0)

__device__ __forceinline__ unsigned short f2b(float f) {
  unsigned int u = __builtin_bit_cast(unsigned int, f);
  u = u + 0x7FFFu + ((u >> 16) & 1u);   // RNE
  return (unsigned short)(u >> 16);
}
__device__ __forceinline__ float bf2f(unsigned short u) {
  unsigned int v = (unsigned int)u << 16;
  return __builtin_bit_cast(float, v);
}
__device__ __forceinline__ us8 pack8(float4 a, float4 b) {
  us8 r;
  r[0] = f2b(a.x); r[1] = f2b(a.y); r[2] = f2b(a.z); r[3] = f2b(a.w);
  r[4] = f2b(b.x); r[5] = f2b(b.y); r[6] = f2b(b.z); r[7] = f2b(b.w);
  return r;
}
__device__ __forceinline__ float sigm(float x) { return 1.0f / (1.0f + __expf(-x)); }
__device__ __forceinline__ float tanh_f(float x) { return 2.0f / (1.0f + __expf(-2.0f * x)) - 1.0f; }
__device__ __forceinline__ f32x16 zz16() {
  f32x16 v;
  #pragma unroll
  for (int i = 0; i < 16; ++i) v[i] = 0.f;
  return v;
}

__global__ void pack_w(const float* __restrict__ a,  // Wioux 768x256
                       const float* __restrict__ b,  // Wiouh 768x256
                       const float* __restrict__ c,  // Wfx   256x256
                       const float* __restrict__ d,  // Wfh   256x256
                       unsigned short* __restrict__ out) {
  int i = blockIdx.x * blockDim.x + threadIdx.x;  // 0 .. 524287
  const int A = 768 * 256;
  const int B = A + 768 * 256;
  const int C = B + 256 * 256;
  float v;
  if (i < A)      v = a[i];
  else if (i < B) v = b[i - A];
  else if (i < C) v = c[i - B];
  else            v = d[i - C];
  out[i] = f2b(v);
}

// convert interior-node x rows to bf16 (8 elems/thread)
__global__ void conv_x(const float* __restrict__ x, unsigned short* __restrict__ xb, int n8) {
  int i = blockIdx.x * blockDim.x + threadIdx.x;
  if (i >= n8) return;
  float4 a = *(const float4*)(x + (size_t)i * 8);
  float4 b = *(const float4*)(x + (size_t)i * 8 + 4);
  *(us8*)(xb + (size_t)i * 8) = pack8(a, b);
}

template<int LEAF>
__global__ __launch_bounds__(512, 2) void level_k(
    const float* __restrict__ xf32,            // leaf path
    const unsigned short* __restrict__ xb,     // interior path (global node idx)
    const unsigned short* __restrict__ Wx,     // bf16 Wioux [768][256]
    const unsigned short* __restrict__ Wh,     // bf16 Wiouh [768][256]
    const unsigned short* __restrict__ Wfxw,   // bf16 Wfx   [256][256]
    const unsigned short* __restrict__ Wfhw,   // bf16 Wfh   [256][256]
    const float* __restrict__ bioux,
    const float* __restrict__ bfx,
    const float* __restrict__ fb,
    float* __restrict__ h_all,                 // d_out + 512, global node idx
    unsigned short* __restrict__ cb_cur,       // level-local [L][256] bf16
    const unsigned short* __restrict__ cb_next,
    unsigned short* __restrict__ hb_cur,
    const unsigned short* __restrict__ hb_next,
    float* __restrict__ out0,                  // d_out (h_root | c_root)
    int s, int L, int T, int root)
{
  extern __shared__ unsigned short sm[];
  unsigned short* Xs  = sm;                       // [MT][LSTR]
  unsigned short* H1s = sm + MT * LSTR;
  unsigned short* H2s = sm + 2 * MT * LSTR;

  const int tid = threadIdx.x;
  const int G   = gridDim.x;

  // staging partition: thread -> (row 0..31, 16-elem chunk)
  const int row = tid >> 4;
  const int ec  = (tid & 15) * 16;

  // MFMA ids
  const int lane = tid & 63;
  const int w    = tid >> 6;
  const int lr   = lane & 31;
  const int kh   = lane >> 5;
  const int koff = kh * 8;
  const int colc = w * 32 + lr;

  const unsigned short* wxp  = Wx   + (size_t)colc * 256;  // i (o:+65536, u:+131072)
  const unsigned short* whp  = Wh   + (size_t)colc * 256;
  const unsigned short* wfxp = Wfxw + (size_t)colc * 256;
  const unsigned short* wfhp = Wfhw + (size_t)colc * 256;

  const float bi_ = bioux[colc];
  const float bo_ = bioux[256 + colc];
  const float bu_ = bioux[512 + colc];
  const float bf_ = LEAF ? 0.f : (bfx[colc] + fb[colc]);

  // ---- staged registers ----
  us8 sx0, sx1, sh10, sh11, sh20, sh21;
  float4 fx0, fx1, fx2, fx3;

  int t = blockIdx.x;
  // prologue loads
  if (LEAF) {
    const float* xp = xf32 + ((size_t)(s + t * MT + row)) * 256 + ec;
    fx0 = *(const float4*)xp;       fx1 = *(const float4*)(xp + 4);
    fx2 = *(const float4*)(xp + 8); fx3 = *(const float4*)(xp + 12);
  } else {
    const unsigned short* xq = xb + ((size_t)(s + t * MT + row)) * 256 + ec;
    sx0 = *(const us8*)xq; sx1 = *(const us8*)(xq + 8);
    const unsigned short* hq = hb_next + ((size_t)(2 * (t * MT + row))) * 256 + ec;
    sh10 = *(const us8*)hq;         sh11 = *(const us8*)(hq + 8);
    sh20 = *(const us8*)(hq + 256); sh21 = *(const us8*)(hq + 264);
  }

  for (; t < T; t += G) {
    const int nb0 = t * MT;

    __syncthreads();   // prior tile's LDS readers done
    if (LEAF) {
      *(us8*)(Xs + row * LSTR + ec)     = pack8(fx0, fx1);
      *(us8*)(Xs + row * LSTR + ec + 8) = pack8(fx2, fx3);
    } else {
      *(us8*)(Xs  + row * LSTR + ec)     = sx0;
      *(us8*)(Xs  + row * LSTR + ec + 8) = sx1;
      *(us8*)(H1s + row * LSTR + ec)     = sh10;
      *(us8*)(H1s + row * LSTR + ec + 8) = sh11;
      *(us8*)(H2s + row * LSTR + ec)     = sh20;
      *(us8*)(H2s + row * LSTR + ec + 8) = sh21;
    }
    __syncthreads();   // LDS tile ready

    const int tn = t + G;
    float cv[16];

    if (!LEAF) {
      // ---- P1: axf = x @ Wfx^T (one plane live) ----
      f32x16 axf = zz16();
      #pragma unroll 2
      for (int kt = 0; kt < 16; ++kt) {
        const int k0 = kt * 16 + koff;
        bf16x8 bv = *(const bf16x8*)(wfxp + k0);
        bf16x8 av = *(const bf16x8*)(Xs + lr * LSTR + k0);
        axf = MFMA32(av, bv, axf);
      }

      // ---- c1 gather (hides under P2a) ----
      float c1v[16];
      #pragma unroll
      for (int r = 0; r < 16; ++r) {
        const int m = (r & 3) + 8 * (r >> 2) + 4 * kh;
        c1v[r] = bf2f(cb_next[(size_t)(2 * (nb0 + m)) * 256 + colc]);
      }

      // ---- P2a: f1 = axf + h1@Wfh^T ----
      f32x16 f1 = axf;
      #pragma unroll 2
      for (int kt = 0; kt < 16; ++kt) {
        const int k0 = kt * 16 + koff;
        bf16x8 bv = *(const bf16x8*)(wfhp + k0);
        bf16x8 av = *(const bf16x8*)(H1s + lr * LSTR + k0);
        f1 = MFMA32(av, bv, f1);
      }
      #pragma unroll
      for (int r = 0; r < 16; ++r) cv[r] = sigm(f1[r] + bf_) * c1v[r];

      // ---- c2 gather (hides under P2b) ----
      float c2v[16];
      #pragma unroll
      for (int r = 0; r < 16; ++r) {
        const int m = (r & 3) + 8 * (r >> 2) + 4 * kh;
        c2v[r] = bf2f(cb_next[(size_t)(2 * (nb0 + m) + 1) * 256 + colc]);
      }

      // ---- P2b: f2 = axf + h2@Wfh^T (axf reused as accumulator) ----
      #pragma unroll 2
      for (int kt = 0; kt < 16; ++kt) {
        const int k0 = kt * 16 + koff;
        bf16x8 bv = *(const bf16x8*)(wfhp + k0);
        bf16x8 av = *(const bf16x8*)(H2s + lr * LSTR + k0);
        axf = MFMA32(av, bv, axf);
      }
      #pragma unroll
      for (int r = 0; r < 16; ++r) cv[r] += sigm(axf[r] + bf_) * c2v[r];

      // ---- issue next tile's staged loads (land during P3) ----
      if (tn < T) {
        const unsigned short* xq = xb + ((size_t)(s + tn * MT + row)) * 256 + ec;
        sx0 = *(const us8*)xq; sx1 = *(const us8*)(xq + 8);
        const unsigned short* hq = hb_next + ((size_t)(2 * (tn * MT + row))) * 256 + ec;
        sh10 = *(const us8*)hq;         sh11 = *(const us8*)(hq + 8);
        sh20 = *(const us8*)(hq + 256); sh21 = *(const us8*)(hq + 264);
      }

      // ---- P3i: ai = x@Wi_x + h1@Wi_h + h2@Wi_h ----
      f32x16 acc = zz16();
      #pragma unroll 1
      for (int kt = 0; kt < 16; ++kt) {
        const int k0 = kt * 16 + koff;
        bf16x8 bx = *(const bf16x8*)(wxp + k0);
        bf16x8 bh = *(const bf16x8*)(whp + k0);
        bf16x8 ax = *(const bf16x8*)(Xs  + lr * LSTR + k0);
        bf16x8 a1 = *(const bf16x8*)(H1s + lr * LSTR + k0);
        bf16x8 a2 = *(const bf16x8*)(H2s + lr * LSTR + k0);
        acc = MFMA32(ax, bx, acc);
        acc = MFMA32(a1, bh, acc);
        acc = MFMA32(a2, bh, acc);
      }
      float ig[16];
      #pragma unroll
      for (int r = 0; r < 16; ++r) ig[r] = sigm(acc[r] + bi_);

      // ---- P3u ----
      acc = zz16();
      #pragma unroll 1
      for (int kt = 0; kt < 16; ++kt) {
        const int k0 = kt * 16 + koff;
        bf16x8 bx = *(const bf16x8*)(wxp + 131072 + k0);
        bf16x8 bh = *(const bf16x8*)(whp + 131072 + k0);
        bf16x8 ax = *(const bf16x8*)(Xs  + lr * LSTR + k0);
        bf16x8 a1 = *(const bf16x8*)(H1s + lr * LSTR + k0);
        bf16x8 a2 = *(const bf16x8*)(H2s + lr * LSTR + k0);
        acc = MFMA32(ax, bx, acc);
        acc = MFMA32(a1, bh, acc);
        acc = MFMA32(a2, bh, acc);
      }
      #pragma unroll
      for (int r = 0; r < 16; ++r) cv[r] += ig[r] * tanh_f(acc[r] + bu_);

      // ---- P3o ----
      acc = zz16();
      #pragma unroll 1
      for (int kt = 0; kt < 16; ++kt) {
        const int k0 = kt * 16 + koff;
        bf16x8 bx = *(const bf16x8*)(wxp + 65536 + k0);
        bf16x8 bh = *(const bf16x8*)(whp + 65536 + k0);
        bf16x8 ax = *(const bf16x8*)(Xs  + lr * LSTR + k0);
        bf16x8 a1 = *(const bf16x8*)(H1s + lr * LSTR + k0);
        bf16x8 a2 = *(const bf16x8*)(H2s + lr * LSTR + k0);
        acc = MFMA32(ax, bx, acc);
        acc = MFMA32(a1, bh, acc);
        acc = MFMA32(a2, bh, acc);
      }

      // ---- epilogue ----
      #pragma unroll
      for (int r = 0; r < 16; ++r) {
        const int m = (r & 3) + 8 * (r >> 2) + 4 * kh;
        const int j = nb0 + m;
        if (j >= L) continue;
        const size_t n = (size_t)(s + j);
        const float c_ = cv[r];
        const float hv = sigm(acc[r] + bo_) * tanh_f(c_);
        h_all[n * 256 + colc] = hv;
        cb_cur[(size_t)j * 256 + colc] = f2b(c_);
        hb_cur[(size_t)j * 256 + colc] = f2b(hv);
        if (root && j == 0) { out0[colc] = hv; out0[256 + colc] = c_; }
      }
    } else {
      // ---- leaf: issue next staged loads, then per-gate passes on x ----
      if (tn < T) {
        const float* xp = xf32 + ((size_t)(s + tn * MT + row)) * 256 + ec;
        fx0 = *(const float4*)xp;       fx1 = *(const float4*)(xp + 4);
        fx2 = *(const float4*)(xp + 8); fx3 = *(const float4*)(xp + 12);
      }

      f32x16 acc = zz16();
      #pragma unroll 1
      for (int kt = 0; kt < 16; ++kt) {
        const int k0 = kt * 16 + koff;
        bf16x8 bx = *(const bf16x8*)(wxp + k0);
        bf16x8 ax = *(const bf16x8*)(Xs + lr * LSTR + k0);
        acc = MFMA32(ax, bx, acc);
      }
      float ig[16];
      #pragma unroll
      for (int r = 0; r < 16; ++r) ig[r] = sigm(acc[r] + bi_);

      acc = zz16();
      #pragma unroll 1
      for (int kt = 0; kt < 16; ++kt) {
        const int k0 = kt * 16 + koff;
        bf16x8 bx = *(const bf16x8*)(wxp + 131072 + k0);
        bf16x8 ax = *(const bf16x8*)(Xs + lr * LSTR + k0);
        acc = MFMA32(ax, bx, acc);
      }
      #pragma unroll
      for (int r = 0; r < 16; ++r) cv[r] = ig[r] * tanh_f(acc[r] + bu_);

      acc = zz16();
      #pragma unroll 1
      for (int kt = 0; kt < 16; ++kt) {
        const int k0 = kt * 16 + koff;
        bf16x8 bx = *(const bf16x8*)(wxp + 65536 + k0);
        bf16x8 ax = *(const bf16x8*)(Xs + lr * LSTR + k0);
        acc = MFMA32(ax, bx, acc);
      }

      #pragma unroll
      for (int r = 0; r < 16; ++r) {
        const int m = (r & 3) + 8 * (r >> 2) + 4 * kh;
        const int j = nb0 + m;
        if (j >= L) continue;
        const size_t n = (size_t)(s + j);
        const float c_ = cv[r];
        const float hv = sigm(acc[r] + bo_) * tanh_f(c_);
        h_all[n * 256 + colc] = hv;
        cb_cur[(size_t)j * 256 + colc] = f2b(c_);
        hb_cur[(size_t)j * 256 + colc] = f2b(hv);
      }
    }
  }
}

extern "C" void kernel_launch(void* const* d_in, const int* in_sizes, int n_in,
                              void* d_out, int out_size, void* d_ws, size_t ws_size,
                              hipStream_t stream) {
  const float* inputs = (const float*)d_in[0];
  const float* Wioux  = (const float*)d_in[1];
  const float* bioux  = (const float*)d_in[2];
  const float* Wiouh  = (const float*)d_in[3];
  const float* Wfx    = (const float*)d_in[4];
  const float* bfx    = (const float*)d_in[5];
  const float* Wfh    = (const float*)d_in[6];
  const float* fb     = (const float*)d_in[7];

  const int N = in_sizes[0] / 256;       // 262143
  int depth = 0;
  while (((1 << depth) - 1) < N) ++depth;  // 18
  const int LF = (N + 1) / 2;            // 131072 leaves

  float* out   = (float*)d_out;
  float* h_all = out + 512;

  // ws carve (bytes): cb ping-pong bf16, hb ping-pong bf16, xb bf16, weights
  char* p = (char*)d_ws;
  unsigned short* cb_even = (unsigned short*)p; p += (size_t)(LF / 2) * 256 * 2;
  unsigned short* cb_odd  = (unsigned short*)p; p += (size_t)LF * 256 * 2;
  unsigned short* hb_even = (unsigned short*)p; p += (size_t)(LF / 2) * 256 * 2;
  unsigned short* hb_odd  = (unsigned short*)p; p += (size_t)LF * 256 * 2;
  unsigned short* xb      = (unsigned short*)p; p += (size_t)LF * 256 * 2;
  unsigned short* wb      = (unsigned short*)p;

  pack_w<<<2048, 256, 0, stream>>>(Wioux, Wiouh, Wfx, Wfh, wb);
  {
    const int n8 = ((LF - 1) * 256) / 8;   // interior-node elems / 8
    conv_x<<<(n8 + 255) / 256, 256, 0, stream>>>(inputs, xb, n8);
  }

  const unsigned short* pWx  = wb;
  const unsigned short* pWh  = wb + 768 * 256;
  const unsigned short* pWfx = wb + 2 * 768 * 256;
  const unsigned short* pWfh = wb + 2 * 768 * 256 + 256 * 256;

  for (int d = depth - 1; d >= 0; --d) {
    const int L = 1 << d;
    const int s = L - 1;
    const int T = (L + MT - 1) / MT;
    const int G = T < 512 ? T : 512;
    unsigned short* cb_cur = (d & 1) ? cb_odd : cb_even;
    const unsigned short* cb_next = ((d + 1) & 1) ? cb_odd : cb_even;
    unsigned short* hb_cur = (d & 1) ? hb_odd : hb_even;
    const unsigned short* hb_next = ((d + 1) & 1) ? hb_odd : hb_even;
    if (d == depth - 1) {
      level_k<1><<<G, 512, (size_t)MT * LSTR * 2, stream>>>(
          inputs, xb, pWx, pWh, pWfx, pWfh, bioux, bfx, fb,
          h_all, cb_cur, cb_next, hb_cur, hb_next, out, s, L, T, 0);
    } else {
      level_k<0><<<G, 512, (size_t)3 * MT * LSTR * 2, stream>>>(
          inputs, xb, pWx, pWh, pWfx, pWfh, bioux, bfx, fb,
          h_all, cb_cur, cb_next, hb_cur, hb_next, out, s, L, T, (d == 0) ? 1 : 0);
    }
  }
}